// Round 1
// baseline (36881.674 us; speedup 1.0000x reference)
//
#include <hip/hip_runtime.h>
#include <math.h>

// Problem dims (fixed by reference setup_inputs)
#define NB  512
#define TT  128
#define DXX 256
#define DUU 32
#define DZZ 128
#define DWW 64
#define MMM 16
#define HHH 128
#define G4  512   // 4*H

__device__ __forceinline__ float sigf(float x){ return 1.f/(1.f+__expf(-x)); }

// ---------------------------------------------------------------------------
// dense: out[r][c] = act(bias[c] + sum_k in[r*ldi+k] * W[c*K+k]), r in [0,4)
// 256-thread block. Thread owns columns g=tid&127 for rows {2*(tid>>7), +1}.
// Weight tile staged in LDS [128 cols][<=64 k] with +65 pad (2-way bank = free).
// K-chunks are always 64 or 32. ACT: 0 none, 1 relu, 2 tanh.
// ---------------------------------------------------------------------------
template<int ACT>
__device__ void dense(const float* __restrict__ W, const float* __restrict__ bias,
                      int C, int K, const float* sIn, int ldi,
                      float* sOut, int ldo, float* sWt)
{
    const int tid = threadIdx.x;
    const int g   = tid & 127;
    const int rq  = tid >> 7;           // 0 or 1
    const int r0  = 2*rq, r1 = 2*rq+1;
    for (int cb = 0; cb < C; cb += 128){
        float acc0 = 0.f, acc1 = 0.f;
        for (int kb = 0; kb < K; kb += 64){
            const int kw = (K - kb < 64) ? (K - kb) : 64;   // 64 or 32
            __syncthreads();   // protect sWt vs previous users
            if (kw == 64){
                for (int l = tid; l < 128*64; l += 256){
                    int gg = l >> 6, kk = l & 63;
                    int c = cb + gg;
                    sWt[gg*65 + kk] = (c < C) ? W[(size_t)c*K + kb + kk] : 0.f;
                }
            } else {
                for (int l = tid; l < 128*32; l += 256){
                    int gg = l >> 5, kk = l & 31;
                    int c = cb + gg;
                    sWt[gg*65 + kk] = (c < C) ? W[(size_t)c*K + kb + kk] : 0.f;
                }
            }
            __syncthreads();
            const float* ip0 = sIn + r0*ldi + kb;
            const float* ip1 = sIn + r1*ldi + kb;
            const float* wp  = sWt + g*65;
            #pragma unroll 8
            for (int k = 0; k < kw; k++){
                float wv = wp[k];
                acc0 += ip0[k]*wv;
                acc1 += ip1[k]*wv;
            }
        }
        int c = cb + g;
        if (c < C){
            float b = bias ? bias[c] : 0.f;
            float v0 = acc0 + b, v1 = acc1 + b;
            if (ACT == 1){ v0 = fmaxf(v0, 0.f); v1 = fmaxf(v1, 0.f); }
            else if (ACT == 2){ v0 = tanhf(v0); v1 = tanhf(v1); }
            sOut[r0*ldo + c] = v0;
            sOut[r1*ldo + c] = v1;
        }
    }
}

// ---------------------------------------------------------------------------
// K1: xg[(n*T+t)][g] = sum_d x[n,t,d]*Wih[g,d] + b[g]   (65536 x 512, K=256)
// fp32 tiled GEMM, 64x64 tile, 4x4 microtile.
// ---------------------------------------------------------------------------
__global__ __launch_bounds__(256) void k_xg(const float* __restrict__ X,
                                            const float* __restrict__ Wih,
                                            const float* __restrict__ b,
                                            float* __restrict__ xg)
{
    __shared__ float sA[32][68];
    __shared__ float sB[32][68];
    const int tid = threadIdx.x;
    const int row0 = blockIdx.x * 64;
    const int col0 = blockIdx.y * 64;
    const int tx = tid & 15, ty = tid >> 4;
    float acc[4][4] = {};
    for (int kb = 0; kb < DXX; kb += 32){
        #pragma unroll
        for (int i = 0; i < 2; i++){
            int qq = tid + i*256;            // 0..511
            int r  = qq >> 3, kc = (qq & 7) * 4;
            float4 av = *(const float4*)&X[(size_t)(row0+r)*DXX + kb + kc];
            sA[kc+0][r]=av.x; sA[kc+1][r]=av.y; sA[kc+2][r]=av.z; sA[kc+3][r]=av.w;
            float4 bv = *(const float4*)&Wih[(size_t)(col0+r)*DXX + kb + kc];
            sB[kc+0][r]=bv.x; sB[kc+1][r]=bv.y; sB[kc+2][r]=bv.z; sB[kc+3][r]=bv.w;
        }
        __syncthreads();
        #pragma unroll
        for (int kk = 0; kk < 32; kk++){
            float4 a4 = *(const float4*)&sA[kk][ty*4];
            float4 b4 = *(const float4*)&sB[kk][tx*4];
            float aa[4]={a4.x,a4.y,a4.z,a4.w}, bb[4]={b4.x,b4.y,b4.z,b4.w};
            #pragma unroll
            for (int i2=0;i2<4;i2++)
                #pragma unroll
                for (int j=0;j<4;j++) acc[i2][j] += aa[i2]*bb[j];
        }
        __syncthreads();
    }
    #pragma unroll
    for (int i2=0;i2<4;i2++){
        int r = row0 + ty*4 + i2;
        #pragma unroll
        for (int j=0;j<4;j++){
            int c = col0 + tx*4 + j;
            xg[(size_t)r*G4 + c] = acc[i2][j] + b[c];
        }
    }
}

// ---------------------------------------------------------------------------
// K2: forward LSTM recurrence over T=128 steps; 4 rows/block, 128 blocks.
// Writes final hidden h0[n][0..127].
// ---------------------------------------------------------------------------
__global__ __launch_bounds__(256) void k_lstm(const float* __restrict__ xg,
                                              const float* __restrict__ Whh,
                                              float* __restrict__ h0)
{
    __shared__ float sH[4*132];
    __shared__ float sC[4*132];
    __shared__ float sG[4*516];
    __shared__ float sWt[128*65];
    const int tid = threadIdx.x;
    const int n0  = blockIdx.x * 4;
    for (int l = tid; l < 4*132; l += 256){ sH[l]=0.f; sC[l]=0.f; }
    for (int t = 0; t < TT; t++){
        dense<0>(Whh, nullptr, 512, 128, sH, 132, sG, 516, sWt);
        __syncthreads();
        for (int l = tid; l < 4*128; l += 256){
            int r = l >> 7, j = l & 127;
            const float* xp = &xg[((size_t)(n0+r)*TT + t)*G4];
            float gi = sG[r*516 +       j] + xp[      j];
            float gf = sG[r*516 + 128 + j] + xp[128 + j];
            float gv = sG[r*516 + 256 + j] + xp[256 + j];
            float go = sG[r*516 + 384 + j] + xp[384 + j];
            float c  = sigf(gf)*sC[r*132+j] + sigf(gi)*tanhf(gv);
            sC[r*132+j] = c;
            sH[r*132+j] = sigf(go)*tanhf(c);
        }
        // next dense's internal barriers order these writes before reads
    }
    __syncthreads();
    for (int l = tid; l < 4*128; l += 256){
        int r = l >> 7, j = l & 127;
        h0[(size_t)(n0+r)*HHH + j] = sH[r*132+j];
    }
}

// ---------------------------------------------------------------------------
// K3: bw-LSTM single step (t=T-1 from zero state) + initial net:
// p0 -> m0,s0 -> w1 -> z1. Writes z[:,0], w_mean[:,0], w_std[:,0].
// ---------------------------------------------------------------------------
__global__ __launch_bounds__(256) void k_init(
    const float* __restrict__ X,
    const float* __restrict__ bw_Wih, const float* __restrict__ bw_b,
    const float* __restrict__ i1w, const float* __restrict__ i1b,
    const float* __restrict__ i2w, const float* __restrict__ i2b,
    const float* __restrict__ z1w, const float* __restrict__ z1b,
    const float* __restrict__ z2w, const float* __restrict__ z2b,
    const float* __restrict__ eps1, const float* __restrict__ h0,
    float* __restrict__ zb, float* __restrict__ wm, float* __restrict__ wsd)
{
    __shared__ float sX[4*260];
    __shared__ float sG[4*516];
    __shared__ float sH0[4*260];
    __shared__ float sT[4*132];
    __shared__ float sP[4*132];
    __shared__ float sWt[128*65];
    const int tid = threadIdx.x;
    const int n0  = blockIdx.x * 4;
    for (int l = tid; l < 4*256; l += 256){
        int r = l >> 8, k = l & 255;
        sX[r*260+k] = X[((size_t)(n0+r)*TT + (TT-1))*DXX + k];
    }
    for (int l = tid; l < 4*128; l += 256){
        int r = l >> 7, j = l & 127;
        sH0[r*260+j] = h0[(size_t)(n0+r)*HHH + j];   // fw half
    }
    dense<0>(bw_Wih, bw_b, 512, 256, sX, 260, sG, 516, sWt);
    __syncthreads();
    for (int l = tid; l < 4*128; l += 256){
        int r = l >> 7, j = l & 127;
        float gi = sG[r*516 + j];
        float gv = sG[r*516 + 256 + j];
        float go = sG[r*516 + 384 + j];
        float c  = sigf(gi)*tanhf(gv);        // c_prev = 0
        sH0[r*260 + 128 + j] = sigf(go)*tanhf(c);
    }
    dense<1>(i1w, i1b, 128, 256, sH0, 260, sT, 132, sWt);
    dense<0>(i2w, i2b, 128, 128, sT, 132, sP, 132, sWt);
    __syncthreads();
    for (int l = tid; l < 4*64; l += 256){
        int r = l >> 6, j = l & 63;
        float m0 = sP[r*132 + j];
        float s0 = __expf(sP[r*132 + 64 + j]) + 1e-5f;
        float w1 = m0 + s0*eps1[(size_t)(n0+r)*DWW + j];
        wm[((size_t)(n0+r)*TT)*DWW + j]  = m0;
        wsd[((size_t)(n0+r)*TT)*DWW + j] = s0;
        sX[r*68 + j] = w1;                    // reuse sX as w1 [4][68]
    }
    dense<1>(z1w, z1b, 128, 64, sX, 68, sT, 132, sWt);
    dense<0>(z2w, z2b, 128, 128, sT, 132, sP, 132, sWt);
    __syncthreads();
    for (int l = tid; l < 4*128; l += 256){
        int r = l >> 7, j = l & 127;
        zb[((size_t)(n0+r)*TT)*DZZ + j] = sP[r*132+j];
    }
}

// ---------------------------------------------------------------------------
// K4: the 127-step recurrent scan. 4 rows/block, 128 blocks, no grid sync.
// sIn row layout: [x(0:256) | z(256:384) | u(384:416) | w(416:480)] pad 484.
// ---------------------------------------------------------------------------
__global__ __launch_bounds__(256) void k_scan(
    const float* __restrict__ X, const float* __restrict__ U, const float* __restrict__ EPS,
    const float* __restrict__ wp_w1, const float* __restrict__ wp_b1,
    const float* __restrict__ wp_w2, const float* __restrict__ wp_b2,
    const float* __restrict__ vp_w1, const float* __restrict__ vp_b1,
    const float* __restrict__ vp_w2, const float* __restrict__ vp_b2,
    const float* __restrict__ Amat, const float* __restrict__ Bmat, const float* __restrict__ Cmat,
    float* __restrict__ zb, float* __restrict__ wm, float* __restrict__ wsd)
{
    __shared__ float sIn[4*484];
    __shared__ float sT [4*132];
    __shared__ float sPW[4*132];
    __shared__ float sV [4*132];
    __shared__ float sAl[4*20];
    __shared__ float sWt[128*65];
    const int tid = threadIdx.x;
    const int n0  = blockIdx.x * 4;
    const int g   = tid & 127;
    const int rq  = tid >> 7;
    const int r0  = 2*rq, r1 = 2*rq + 1;

    for (int l = tid; l < 4*128; l += 256){
        int r = l >> 7, j = l & 127;
        sIn[r*484 + 256 + j] = zb[((size_t)(n0+r)*TT)*DZZ + j];
    }

    for (int t = 0; t < TT-1; t++){
        // stage x_{t+1}, u_t  (z already in place; w written below)
        for (int l = tid; l < 4*256; l += 256){
            int r = l >> 8, d = l & 255;
            sIn[r*484 + d] = X[((size_t)(n0+r)*TT + t+1)*DXX + d];
        }
        for (int l = tid; l < 4*32; l += 256){
            int r = l >> 5, d = l & 31;
            sIn[r*484 + 384 + d] = U[((size_t)(n0+r)*TT + t)*DUU + d];
        }
        dense<2>(wp_w1, wp_b1, 128, 416, sIn, 484, sT, 132, sWt);
        dense<0>(wp_w2, wp_b2, 128, 128, sT, 132, sPW, 132, sWt);
        __syncthreads();
        {   // w_t = m + s*eps, store stats
            int r = tid >> 6, j = tid & 63;
            float mv = sPW[r*132 + j];
            float sv = __expf(sPW[r*132 + 64 + j]) + 0.01f;
            float ev = EPS[((size_t)(n0+r)*TT + t+1)*DWW + j];
            sIn[r*484 + 416 + j] = mv + sv*ev;
            wm [((size_t)(n0+r)*TT + t+1)*DWW + j] = mv;
            wsd[((size_t)(n0+r)*TT + t+1)*DWW + j] = sv;
        }
        dense<1>(vp_w1, vp_b1, 128, 160, sIn + 256, 484, sV, 132, sWt);
        dense<0>(vp_w2, vp_b2,  16, 128, sV, 132, sAl, 20, sWt);
        __syncthreads();
        if (tid < 4){
            float mx = -1e30f;
            for (int m2 = 0; m2 < 16; m2++) mx = fmaxf(mx, sAl[tid*20+m2]);
            float ssum = 0.f;
            for (int m2 = 0; m2 < 16; m2++){
                float e = __expf(sAl[tid*20+m2] - mx);
                sAl[tid*20+m2] = e; ssum += e;
            }
            float inv = 1.f/ssum;
            for (int m2 = 0; m2 < 16; m2++) sAl[tid*20+m2] *= inv;
        }
        __syncthreads();
        // z_{t+1}[r][i] = sum_m alpha[r][m] * ( [A_m|B_m|C_m] . [z|u|w][r] )
        float z0 = 0.f, z1v = 0.f;
        for (int m2 = 0; m2 < 16; m2++){
            float a0 = 0.f, a1 = 0.f;
            for (int kb = 0; kb < 224; kb += 64){
                const int kw = (224 - kb < 64) ? 32 : 64;
                __syncthreads();
                if (kw == 64){
                    for (int l = tid; l < 128*64; l += 256){
                        int gg = l >> 6, kk = l & 63;
                        int k  = kb + kk;
                        int row = m2*128 + gg;
                        float v;
                        if (k < 128)      v = Amat[(size_t)row*128 + k];
                        else if (k < 160) v = Bmat[(size_t)row*32  + (k-128)];
                        else              v = Cmat[(size_t)row*64  + (k-160)];
                        sWt[gg*65 + kk] = v;
                    }
                } else {
                    for (int l = tid; l < 128*32; l += 256){
                        int gg = l >> 5, kk = l & 31;
                        int k  = kb + kk;           // 192..223 -> C
                        int row = m2*128 + gg;
                        sWt[gg*65 + kk] = Cmat[(size_t)row*64 + (k-160)];
                    }
                }
                __syncthreads();
                const float* ip0 = sIn + r0*484 + 256 + kb;
                const float* ip1 = sIn + r1*484 + 256 + kb;
                const float* wp  = sWt + g*65;
                #pragma unroll 8
                for (int k = 0; k < kw; k++){
                    float wv = wp[k];
                    a0 += ip0[k]*wv;
                    a1 += ip1[k]*wv;
                }
            }
            z0  += sAl[r0*20 + m2]*a0;
            z1v += sAl[r1*20 + m2]*a1;
        }
        __syncthreads();   // all reads of old z done
        sIn[r0*484 + 256 + g] = z0;
        sIn[r1*484 + 256 + g] = z1v;
        zb[((size_t)(n0+r0)*TT + t+1)*DZZ + g] = z0;
        zb[((size_t)(n0+r1)*TT + t+1)*DZZ + g] = z1v;
    }
}

// ---------------------------------------------------------------------------
// K5: reconstruction + squared-error partial sum. 4 (n,t)-rows per block.
// ---------------------------------------------------------------------------
__global__ __launch_bounds__(256) void k_ob(const float* __restrict__ X,
                                            const float* __restrict__ zb,
                                            const float* __restrict__ w1, const float* __restrict__ b1,
                                            const float* __restrict__ w2, const float* __restrict__ b2,
                                            float* __restrict__ acc)
{
    __shared__ float sZ[4*132];
    __shared__ float sT[4*132];
    __shared__ float sXR[4*260];
    __shared__ float sWt[128*65];
    __shared__ float red[4];
    const int tid = threadIdx.x;
    const size_t row0 = (size_t)blockIdx.x * 4;
    for (int l = tid; l < 4*128; l += 256){
        int r = l >> 7, j = l & 127;
        sZ[r*132+j] = zb[(row0+r)*DZZ + j];
    }
    dense<1>(w1, b1, 128, 128, sZ, 132, sT, 132, sWt);
    dense<0>(w2, b2, 256, 128, sT, 132, sXR, 260, sWt);
    __syncthreads();
    float s = 0.f;
    for (int l = tid; l < 4*256; l += 256){
        int r = l >> 8, d = l & 255;
        float e = X[(row0+r)*DXX + d] - sXR[r*260+d];
        s += e*e;
    }
    for (int o = 32; o > 0; o >>= 1) s += __shfl_down(s, o);
    if ((tid & 63) == 0) red[tid >> 6] = s;
    __syncthreads();
    if (tid == 0) atomicAdd(acc, red[0]+red[1]+red[2]+red[3]);
}

// ---------------------------------------------------------------------------
// K6: KL partial sums: S2=sum(std), S3=sum(mean^2), S4=sum(log std)
// ---------------------------------------------------------------------------
__global__ __launch_bounds__(256) void k_kl(const float* __restrict__ wm,
                                            const float* __restrict__ wsd,
                                            float* __restrict__ acc)
{
    __shared__ float red[3][4];
    const int tid = threadIdx.x;
    const size_t base = (size_t)blockIdx.x * 4096 + tid;
    float s2 = 0.f, s3 = 0.f, s4 = 0.f;
    #pragma unroll
    for (int it = 0; it < 16; it++){
        size_t i = base + (size_t)it*256;
        float sd = wsd[i], mv = wm[i];
        s2 += sd; s3 += mv*mv; s4 += __logf(sd);
    }
    for (int o = 32; o > 0; o >>= 1){
        s2 += __shfl_down(s2, o); s3 += __shfl_down(s3, o); s4 += __shfl_down(s4, o);
    }
    if ((tid & 63) == 0){ int w = tid >> 6; red[0][w]=s2; red[1][w]=s3; red[2][w]=s4; }
    __syncthreads();
    if (tid == 0) atomicAdd(acc+1, red[0][0]+red[0][1]+red[0][2]+red[0][3]);
    if (tid == 1) atomicAdd(acc+2, red[1][0]+red[1][1]+red[1][2]+red[1][3]);
    if (tid == 2) atomicAdd(acc+3, red[2][0]+red[2][1]+red[2][2]+red[2][3]);
}

__global__ void k_final(const float* __restrict__ acc, float* __restrict__ out)
{
    if (threadIdx.x == 0 && blockIdx.x == 0){
        const double LOG2PI = 1.8378770664093453;
        double logpx_c = 0.5 * (double)NB * TT * DXX * LOG2PI;     // const part
        double kl = 0.5 * ((double)acc[1] + (double)acc[2]
                           - (double)NB*TT*DWW - (double)acc[3]);
        out[0] = (float)(0.5*(double)acc[0] + logpx_c + kl);
    }
}

// ---------------------------------------------------------------------------
extern "C" void kernel_launch(void* const* d_in, const int* in_sizes, int n_in,
                              void* d_out, int out_size, void* d_ws, size_t ws_size,
                              hipStream_t stream)
{
    (void)in_sizes; (void)n_in; (void)out_size; (void)ws_size;
    const float* x      = (const float*)d_in[0];
    const float* u      = (const float*)d_in[1];
    const float* eps1   = (const float*)d_in[2];
    const float* eps    = (const float*)d_in[3];
    const float* fw_Wih = (const float*)d_in[4];
    const float* fw_Whh = (const float*)d_in[5];
    const float* fw_b   = (const float*)d_in[6];
    const float* bw_Wih = (const float*)d_in[7];
    // d_in[8] = bw_Whh: unused (bw step starts from h=0)
    const float* bw_b   = (const float*)d_in[9];
    const float* i1w = (const float*)d_in[10];
    const float* i1b = (const float*)d_in[11];
    const float* i2w = (const float*)d_in[12];
    const float* i2b = (const float*)d_in[13];
    const float* z1w = (const float*)d_in[14];
    const float* z1b = (const float*)d_in[15];
    const float* z2w = (const float*)d_in[16];
    const float* z2b = (const float*)d_in[17];
    const float* wp_w1 = (const float*)d_in[18];
    const float* wp_b1 = (const float*)d_in[19];
    const float* wp_w2 = (const float*)d_in[20];
    const float* wp_b2 = (const float*)d_in[21];
    const float* vp_w1 = (const float*)d_in[22];
    const float* vp_b1 = (const float*)d_in[23];
    const float* vp_w2 = (const float*)d_in[24];
    const float* vp_b2 = (const float*)d_in[25];
    const float* ob_w1 = (const float*)d_in[26];
    const float* ob_b1 = (const float*)d_in[27];
    const float* ob_w2 = (const float*)d_in[28];
    const float* ob_b2 = (const float*)d_in[29];
    const float* Amat  = (const float*)d_in[30];
    const float* Bmat  = (const float*)d_in[31];
    const float* Cmat  = (const float*)d_in[32];
    float* out = (float*)d_out;

    // workspace layout (floats): ~202 MB total
    float* ws  = (float*)d_ws;
    float* xg  = ws;                                     // N*T*4H  = 33,554,432
    float* h0  = xg  + (size_t)NB*TT*G4;                 // N*H     =     65,536
    float* zb  = h0  + (size_t)NB*HHH;                   // N*T*DZ  =  8,388,608
    float* wm  = zb  + (size_t)NB*TT*DZZ;                // N*T*DW  =  4,194,304
    float* wsd = wm  + (size_t)NB*TT*DWW;                // N*T*DW  =  4,194,304
    float* acc = wsd + (size_t)NB*TT*DWW;                // 4 accumulators

    hipMemsetAsync(acc, 0, 4*sizeof(float), stream);

    k_xg  <<<dim3(NB*TT/64, G4/64), 256, 0, stream>>>(x, fw_Wih, fw_b, xg);
    k_lstm<<<NB/4, 256, 0, stream>>>(xg, fw_Whh, h0);
    k_init<<<NB/4, 256, 0, stream>>>(x, bw_Wih, bw_b, i1w, i1b, i2w, i2b,
                                     z1w, z1b, z2w, z2b, eps1, h0, zb, wm, wsd);
    k_scan<<<NB/4, 256, 0, stream>>>(x, u, eps, wp_w1, wp_b1, wp_w2, wp_b2,
                                     vp_w1, vp_b1, vp_w2, vp_b2,
                                     Amat, Bmat, Cmat, zb, wm, wsd);
    k_ob  <<<NB*TT/4, 256, 0, stream>>>(x, zb, ob_w1, ob_b1, ob_w2, ob_b2, acc);
    k_kl  <<<NB*TT*DWW/4096, 256, 0, stream>>>(wm, wsd, acc);
    k_final<<<1, 64, 0, stream>>>(acc, out);
}

// Round 2
// 5180.607 us; speedup vs baseline: 7.1192x; 7.1192x over previous
//
#include <hip/hip_runtime.h>
#include <stdint.h>
#include <math.h>

// Problem dims (fixed by reference setup_inputs)
#define NB  512
#define TT  128
#define DXX 256
#define DUU 32
#define DZZ 128
#define DWW 64
#define MMM 16
#define HHH 128
#define G4  512   // 4*H

__device__ __forceinline__ float sigf(float x){ return 1.f/(1.f+__expf(-x)); }
__device__ __forceinline__ float fast_tanh(float x){
    float e = __expf(2.f*x);
    return 1.f - 2.f/(e + 1.f);
}
__device__ __forceinline__ unsigned short f2bf(float f){
    uint32_t u = __float_as_uint(f);
    uint32_t r = (u + 0x7fffu + ((u >> 16) & 1u)) >> 16;
    return (unsigned short)r;
}

// ---------------------------------------------------------------------------
// Async stage of one 32KB tile (pre-swizzled bf16 image) global -> LDS.
// 256 threads; LDS dest is linear (global_load_lds: wave-uniform base+lane*16).
// ---------------------------------------------------------------------------
__device__ __forceinline__ void stage32k(const void* gsrc, void* ldst, int tid)
{
    const char* g = (const char*)gsrc;
    char* l = (char*)ldst;
    const int lane = tid & 63;
    const int wv   = tid >> 6;
    #pragma unroll
    for (int it = 0; it < 8; it++){
        const int off = it*4096 + wv*1024;
        __builtin_amdgcn_global_load_lds(
            (const __attribute__((address_space(1))) void*)(g + off + lane*16),
            (__attribute__((address_space(3))) void*)(l + off),
            16, 0, 0);
    }
}

// Tile format: 128 rows (output cols) x 128 k, bf16. Row g at byte g*256.
// Weight(g,k) lives at byte  g*256 + (((k>>3) ^ (g&7))<<4) + (k&7)*2.
// So reading 16B slot s of row g yields k = s*8 .. s*8+7 in order.

// ---------------------------------------------------------------------------
// tile_mac: thread (c=tid&31, kq=tid>>5) accumulates 4 cols {c+32i} x 2 rows
// over its 16-k slice of a 128-k tile. Inputs are f32 rows in LDS (broadcast).
// ---------------------------------------------------------------------------
__device__ __forceinline__ void tile_mac(const char* __restrict__ sWt,
                                         const float* __restrict__ in0,
                                         const float* __restrict__ in1,
                                         int c, int kq, float a[4][2])
{
    const int k0 = kq*16;
    #pragma unroll
    for (int s2 = 0; s2 < 2; s2++){
        const int s = kq*2 + s2;
        const float* p0 = in0 + k0 + s2*8;
        const float* p1 = in1 + k0 + s2*8;
        float4 x0 = *(const float4*)p0;
        float4 y0 = *(const float4*)(p0+4);
        float4 x1 = *(const float4*)p1;
        float4 y1 = *(const float4*)(p1+4);
        float i0[8] = {x0.x,x0.y,x0.z,x0.w,y0.x,y0.y,y0.z,y0.w};
        float i1[8] = {x1.x,x1.y,x1.z,x1.w,y1.x,y1.y,y1.z,y1.w};
        #pragma unroll
        for (int i = 0; i < 4; i++){
            const int g = c + 32*i;
            const uint32_t* wp = (const uint32_t*)(sWt + g*256 + ((s ^ (g & 7)) << 4));
            #pragma unroll
            for (int d = 0; d < 4; d++){
                const uint32_t w2 = wp[d];
                const float wlo = __uint_as_float(w2 << 16);
                const float whi = __uint_as_float(w2 & 0xffff0000u);
                a[i][0] = fmaf(wlo, i0[2*d],   a[i][0]);
                a[i][1] = fmaf(wlo, i1[2*d],   a[i][1]);
                a[i][0] = fmaf(whi, i0[2*d+1], a[i][0]);
                a[i][1] = fmaf(whi, i1[2*d+1], a[i][1]);
            }
        }
    }
}

// ---------------------------------------------------------------------------
// reduce_out: sum partials over the 8 kq groups -> 128(x2-row) outputs,
// apply bias/activation, write to LDS rows (and optionally global).
// ACT: 0 none, 1 relu, 2 tanh
// ---------------------------------------------------------------------------
template<int ACT>
__device__ __forceinline__ void reduce_out(const float a[4][2], float* sRed, int tid,
                                           int C, float biasv,
                                           float* o0, float* o1,
                                           float* g0, float* g1)
{
    #pragma unroll
    for (int i = 0; i < 4; i++){
        sRed[tid*9 + i*2 + 0] = a[i][0];
        sRed[tid*9 + i*2 + 1] = a[i][1];
    }
    __syncthreads();
    const int col = tid >> 1, r = tid & 1;
    if (col < C){
        const int cc = col & 31, ii = col >> 5;
        float s = 0.f;
        #pragma unroll
        for (int q = 0; q < 8; q++) s += sRed[(q*32 + cc)*9 + ii*2 + r];
        s += biasv;
        if (ACT == 1) s = fmaxf(s, 0.f);
        else if (ACT == 2) s = fast_tanh(s);
        (r ? o1 : o0)[col] = s;
        if (g0) (r ? g1 : g0)[col] = s;
    }
    __syncthreads();
}

// ---------------------------------------------------------------------------
// k_prep: convert weights fp32 -> bf16 pre-swizzled 32KB tile images.
// tiles 0..39: scan blob; 40..43: lstm Whh; 44..46: ob
// ---------------------------------------------------------------------------
__global__ __launch_bounds__(256) void k_prep(
    const float* __restrict__ wp_w1, const float* __restrict__ wp_w2,
    const float* __restrict__ vp_w1, const float* __restrict__ vp_w2,
    const float* __restrict__ Amat,  const float* __restrict__ Bmat,
    const float* __restrict__ Cmat,  const float* __restrict__ Whh,
    const float* __restrict__ ob_w1, const float* __restrict__ ob_w2,
    unsigned short* __restrict__ bscan, unsigned short* __restrict__ blstm,
    unsigned short* __restrict__ bob)
{
    const int tile = blockIdx.x;
    unsigned short* dst; int lt;
    if (tile < 40){ dst = bscan + (size_t)tile*16384; lt = 0; }
    else if (tile < 44){ dst = blstm + (size_t)(tile-40)*16384; lt = 1; }
    else { dst = bob + (size_t)(tile-44)*16384; lt = 2; }
    for (int e = threadIdx.x; e < 16384; e += 256){
        const int g = e >> 7, p = e & 127;
        const int s = p >> 3, j = p & 7;
        const int k = ((s ^ (g & 7)) << 3) | j;
        float v = 0.f;
        if (lt == 0){
            if (tile < 4){ int ks = tile*128 + k; if (ks < 416) v = wp_w1[g*416 + ks]; }
            else if (tile == 4){ v = wp_w2[g*128 + k]; }
            else if (tile == 5){ v = vp_w1[g*160 + k]; }
            else if (tile == 6){ if (k < 32) v = vp_w1[g*160 + 128 + k]; }
            else if (tile == 7){ if (g < 16) v = vp_w2[g*128 + k]; }
            else {
                const int m = (tile-8) >> 1, half = (tile-8) & 1;
                const int row = m*128 + g;
                if (half == 0) v = Amat[(size_t)row*128 + k];
                else {
                    if (k < 32)      v = Bmat[(size_t)row*32 + k];
                    else if (k < 96) v = Cmat[(size_t)row*64 + (k-32)];
                }
            }
        } else if (lt == 1){
            const int ct = tile - 40;
            v = Whh[(size_t)(ct*128 + g)*128 + k];
        } else {
            const int tt = tile - 44;
            if (tt == 0) v = ob_w1[g*128 + k];
            else         v = ob_w2[(size_t)((tt-1)*128 + g)*128 + k];
        }
        dst[e] = f2bf(v);
    }
}

// ---------------------------------------------------------------------------
// old fp32 dense helper (still used by k_init, one-shot kernel)
// ---------------------------------------------------------------------------
template<int ACT>
__device__ void dense(const float* __restrict__ W, const float* __restrict__ bias,
                      int C, int K, const float* sIn, int ldi,
                      float* sOut, int ldo, float* sWt)
{
    const int tid = threadIdx.x;
    const int g   = tid & 127;
    const int rq  = tid >> 7;
    const int r0  = 2*rq, r1 = 2*rq+1;
    for (int cb = 0; cb < C; cb += 128){
        float acc0 = 0.f, acc1 = 0.f;
        for (int kb = 0; kb < K; kb += 64){
            const int kw = (K - kb < 64) ? (K - kb) : 64;
            __syncthreads();
            if (kw == 64){
                for (int l = tid; l < 128*64; l += 256){
                    int gg = l >> 6, kk = l & 63;
                    int cx = cb + gg;
                    sWt[gg*65 + kk] = (cx < C) ? W[(size_t)cx*K + kb + kk] : 0.f;
                }
            } else {
                for (int l = tid; l < 128*32; l += 256){
                    int gg = l >> 5, kk = l & 31;
                    int cx = cb + gg;
                    sWt[gg*65 + kk] = (cx < C) ? W[(size_t)cx*K + kb + kk] : 0.f;
                }
            }
            __syncthreads();
            const float* ip0 = sIn + r0*ldi + kb;
            const float* ip1 = sIn + r1*ldi + kb;
            const float* wp  = sWt + g*65;
            #pragma unroll 8
            for (int k = 0; k < kw; k++){
                float wv = wp[k];
                acc0 += ip0[k]*wv;
                acc1 += ip1[k]*wv;
            }
        }
        int cx = cb + g;
        if (cx < C){
            float b = bias ? bias[cx] : 0.f;
            float v0 = acc0 + b, v1 = acc1 + b;
            if (ACT == 1){ v0 = fmaxf(v0, 0.f); v1 = fmaxf(v1, 0.f); }
            else if (ACT == 2){ v0 = fast_tanh(v0); v1 = fast_tanh(v1); }
            sOut[r0*ldo + cx] = v0;
            sOut[r1*ldo + cx] = v1;
        }
    }
}

// ---------------------------------------------------------------------------
// K1: xg[(n*T+t)][g] = sum_d x[n,t,d]*Wih[g,d] + b[g]  (fp32 GEMM, unchanged)
// ---------------------------------------------------------------------------
__global__ __launch_bounds__(256) void k_xg(const float* __restrict__ X,
                                            const float* __restrict__ Wih,
                                            const float* __restrict__ b,
                                            float* __restrict__ xg)
{
    __shared__ float sA[32][68];
    __shared__ float sB[32][68];
    const int tid = threadIdx.x;
    const int row0 = blockIdx.x * 64;
    const int col0 = blockIdx.y * 64;
    const int tx = tid & 15, ty = tid >> 4;
    float acc[4][4] = {};
    for (int kb = 0; kb < DXX; kb += 32){
        #pragma unroll
        for (int i = 0; i < 2; i++){
            int qq = tid + i*256;
            int r  = qq >> 3, kc = (qq & 7) * 4;
            float4 av = *(const float4*)&X[(size_t)(row0+r)*DXX + kb + kc];
            sA[kc+0][r]=av.x; sA[kc+1][r]=av.y; sA[kc+2][r]=av.z; sA[kc+3][r]=av.w;
            float4 bv = *(const float4*)&Wih[(size_t)(col0+r)*DXX + kb + kc];
            sB[kc+0][r]=bv.x; sB[kc+1][r]=bv.y; sB[kc+2][r]=bv.z; sB[kc+3][r]=bv.w;
        }
        __syncthreads();
        #pragma unroll
        for (int kk = 0; kk < 32; kk++){
            float4 a4 = *(const float4*)&sA[kk][ty*4];
            float4 b4 = *(const float4*)&sB[kk][tx*4];
            float aa[4]={a4.x,a4.y,a4.z,a4.w}, bb[4]={b4.x,b4.y,b4.z,b4.w};
            #pragma unroll
            for (int i2=0;i2<4;i2++)
                #pragma unroll
                for (int j=0;j<4;j++) acc[i2][j] += aa[i2]*bb[j];
        }
        __syncthreads();
    }
    #pragma unroll
    for (int i2=0;i2<4;i2++){
        int r = row0 + ty*4 + i2;
        #pragma unroll
        for (int j=0;j<4;j++){
            int cx = col0 + tx*4 + j;
            xg[(size_t)r*G4 + cx] = acc[i2][j] + b[cx];
        }
    }
}

// ---------------------------------------------------------------------------
// K2: forward LSTM: Whh persists in LDS as bf16 tiles. 2 rows/block, 256 blks.
// ---------------------------------------------------------------------------
__global__ __launch_bounds__(256) void k_lstm(const float* __restrict__ xg,
                                              const unsigned short* __restrict__ blob,
                                              float* __restrict__ h0)
{
    __shared__ __align__(16) char sWh[4][32768];
    __shared__ __align__(16) float sHh[2][128];
    const int tid = threadIdx.x;
    const int n0 = blockIdx.x * 2;
    const int g = tid & 127, rh = tid >> 7;
    #pragma unroll
    for (int i = 0; i < 4; i++)
        stage32k((const char*)blob + (size_t)i*32768, sWh[i], tid);
    sHh[tid >> 7][tid & 127] = 0.f;
    float cc = 0.f;
    asm volatile("s_waitcnt vmcnt(0)" ::: "memory");
    __syncthreads();
    const size_t xbase = ((size_t)(n0+rh)*TT)*G4 + g;
    for (int t = 0; t < TT; t++){
        float xv[4];
        #pragma unroll
        for (int ct = 0; ct < 4; ct++) xv[ct] = xg[xbase + (size_t)t*G4 + ct*128];
        float a[4] = {0.f,0.f,0.f,0.f};
        #pragma unroll
        for (int s = 0; s < 16; s++){
            const float* ip = &sHh[rh][s*8];
            float4 u0 = *(const float4*)ip;
            float4 u1 = *(const float4*)(ip+4);
            float in[8] = {u0.x,u0.y,u0.z,u0.w,u1.x,u1.y,u1.z,u1.w};
            #pragma unroll
            for (int ct = 0; ct < 4; ct++){
                const uint32_t* wp = (const uint32_t*)(sWh[ct] + g*256 + ((s ^ (g & 7)) << 4));
                #pragma unroll
                for (int d = 0; d < 4; d++){
                    uint32_t w2 = wp[d];
                    a[ct] = fmaf(__uint_as_float(w2 << 16),        in[2*d],   a[ct]);
                    a[ct] = fmaf(__uint_as_float(w2 & 0xffff0000u), in[2*d+1], a[ct]);
                }
            }
        }
        __syncthreads();   // all dense reads of sHh done
        float ii = sigf(a[0] + xv[0]);
        float ff = sigf(a[1] + xv[1]);
        float gg = fast_tanh(a[2] + xv[2]);
        float oo = sigf(a[3] + xv[3]);
        cc = ff*cc + ii*gg;
        float hh = oo*fast_tanh(cc);
        sHh[rh][g] = hh;
        __syncthreads();
    }
    h0[(size_t)(n0+rh)*HHH + g] = sHh[rh][g];
}

// ---------------------------------------------------------------------------
// K3: bw-LSTM single step + init net (unchanged fp32, one-shot)
// ---------------------------------------------------------------------------
__global__ __launch_bounds__(256) void k_init(
    const float* __restrict__ X,
    const float* __restrict__ bw_Wih, const float* __restrict__ bw_b,
    const float* __restrict__ i1w, const float* __restrict__ i1b,
    const float* __restrict__ i2w, const float* __restrict__ i2b,
    const float* __restrict__ z1w, const float* __restrict__ z1b,
    const float* __restrict__ z2w, const float* __restrict__ z2b,
    const float* __restrict__ eps1, const float* __restrict__ h0,
    float* __restrict__ zb, float* __restrict__ wm, float* __restrict__ wsd)
{
    __shared__ float sX[4*260];
    __shared__ float sG[4*516];
    __shared__ float sH0[4*260];
    __shared__ float sT[4*132];
    __shared__ float sP[4*132];
    __shared__ float sWt[128*65];
    const int tid = threadIdx.x;
    const int n0  = blockIdx.x * 4;
    for (int l = tid; l < 4*256; l += 256){
        int r = l >> 8, k = l & 255;
        sX[r*260+k] = X[((size_t)(n0+r)*TT + (TT-1))*DXX + k];
    }
    for (int l = tid; l < 4*128; l += 256){
        int r = l >> 7, j = l & 127;
        sH0[r*260+j] = h0[(size_t)(n0+r)*HHH + j];
    }
    dense<0>(bw_Wih, bw_b, 512, 256, sX, 260, sG, 516, sWt);
    __syncthreads();
    for (int l = tid; l < 4*128; l += 256){
        int r = l >> 7, j = l & 127;
        float gi = sG[r*516 + j];
        float gv = sG[r*516 + 256 + j];
        float go = sG[r*516 + 384 + j];
        float c  = sigf(gi)*fast_tanh(gv);
        sH0[r*260 + 128 + j] = sigf(go)*fast_tanh(c);
    }
    dense<1>(i1w, i1b, 128, 256, sH0, 260, sT, 132, sWt);
    dense<0>(i2w, i2b, 128, 128, sT, 132, sP, 132, sWt);
    __syncthreads();
    for (int l = tid; l < 4*64; l += 256){
        int r = l >> 6, j = l & 63;
        float m0 = sP[r*132 + j];
        float s0 = __expf(sP[r*132 + 64 + j]) + 1e-5f;
        float w1 = m0 + s0*eps1[(size_t)(n0+r)*DWW + j];
        wm[((size_t)(n0+r)*TT)*DWW + j]  = m0;
        wsd[((size_t)(n0+r)*TT)*DWW + j] = s0;
        sX[r*68 + j] = w1;
    }
    dense<1>(z1w, z1b, 128, 64, sX, 68, sT, 132, sWt);
    dense<0>(z2w, z2b, 128, 128, sT, 132, sP, 132, sWt);
    __syncthreads();
    for (int l = tid; l < 4*128; l += 256){
        int r = l >> 7, j = l & 127;
        zb[((size_t)(n0+r)*TT)*DZZ + j] = sP[r*132+j];
    }
}

// ---------------------------------------------------------------------------
// K4: 127-step scan. 2 rows/block, 256 blocks. bf16 tiles, 2-phase pipeline.
// Unified input vector v = [x(0:256) | z(256:384) | u(384:416) | w(416:480) | 0]
// ---------------------------------------------------------------------------
#define ENDPH() do { asm volatile("s_waitcnt vmcnt(0)" ::: "memory"); __syncthreads(); par ^= 1; } while(0)

__global__ __launch_bounds__(256) void k_scan(
    const float* __restrict__ X, const float* __restrict__ U, const float* __restrict__ EPS,
    const float* __restrict__ wp_b1, const float* __restrict__ wp_b2,
    const float* __restrict__ vp_b1, const float* __restrict__ vp_b2,
    const unsigned short* __restrict__ blob,
    float* __restrict__ zb, float* __restrict__ wm, float* __restrict__ wsd)
{
    __shared__ __align__(16) char  sW[2][32768];
    __shared__ __align__(16) float sV[2][512];
    __shared__ __align__(16) float sH1[2][128];
    __shared__ __align__(16) float sH2[2][128];
    __shared__ __align__(16) float sPW[2][128];
    __shared__ float sL[2][16];
    __shared__ float sAl[2][16];
    __shared__ float sRed[256*9];
    const int tid = threadIdx.x;
    const int n0  = blockIdx.x * 2;
    const int c   = tid & 31, kq = tid >> 5;
    const int rcol = tid >> 1;
    float b_wp1 = 0.f, b_wp2 = 0.f, b_vp1 = 0.f, b_vp2 = 0.f;
    if (rcol < 128){ b_wp1 = wp_b1[rcol]; b_wp2 = wp_b2[rcol]; b_vp1 = vp_b1[rcol]; }
    if (rcol < 16){ b_vp2 = vp_b2[rcol]; }

    {   // init sV: x_1 | z_0 | u_0 | w=0 | pad=0
        const int r = tid >> 7, q = tid & 127;
        float2 xv = *(const float2*)&X[(((size_t)(n0+r)*TT) + 1)*DXX + q*2];
        sV[r][q*2]   = xv.x;
        sV[r][q*2+1] = xv.y;
        sV[r][256+q] = zb[(((size_t)(n0+r)*TT))*DZZ + q];
        if (q < 32)  sV[r][384+q] = U[(((size_t)(n0+r)*TT))*DUU + q];
        if (q < 64)  sV[r][416+q] = 0.f;
        if (q >= 96) sV[r][384+q] = 0.f;
    }
    stage32k(blob, sW[0], tid);
    asm volatile("s_waitcnt vmcnt(0)" ::: "memory");
    __syncthreads();
    int par = 0;

    for (int t = 0; t < TT-1; t++){
        float epsv = 0.f;
        if (tid < 128){
            const int r = tid >> 6, j = tid & 63;
            epsv = EPS[(((size_t)(n0+r)*TT) + t+1)*DWW + j];
        }
        int tile = 0;
        float a[4][2];
        // ---- G1: tanh(wp_w1 . v + b1) -> sH1 (tiles 0..3)
        #pragma unroll
        for (int i=0;i<4;i++){ a[i][0]=0.f; a[i][1]=0.f; }
        for (int ch = 0; ch < 4; ch++){
            if (!(t == TT-2 && tile == 39))
                stage32k((const char*)blob + (size_t)((tile+1)%40)*32768, sW[par^1], tid);
            tile_mac(sW[par], &sV[0][ch*128], &sV[1][ch*128], c, kq, a);
            tile++;
            if (ch == 3) reduce_out<2>(a, sRed, tid, 128, b_wp1, sH1[0], sH1[1], nullptr, nullptr);
            ENDPH();
        }
        // ---- G2: pw = wp_w2 . h1 + b2 (tile 4); then w update
        #pragma unroll
        for (int i=0;i<4;i++){ a[i][0]=0.f; a[i][1]=0.f; }
        stage32k((const char*)blob + (size_t)((tile+1)%40)*32768, sW[par^1], tid);
        tile_mac(sW[par], sH1[0], sH1[1], c, kq, a);
        tile++;
        reduce_out<0>(a, sRed, tid, 128, b_wp2, sPW[0], sPW[1], nullptr, nullptr);
        if (tid < 128){
            const int r = tid >> 6, j = tid & 63;
            float mv = sPW[r][j];
            float sv = __expf(sPW[r][64+j]) + 0.01f;
            sV[r][416+j] = mv + sv*epsv;
            wm [(((size_t)(n0+r)*TT) + t+1)*DWW + j] = mv;
            wsd[(((size_t)(n0+r)*TT) + t+1)*DWW + j] = sv;
        }
        ENDPH();
        // ---- G3: relu(vp_w1 . [z|u] + b) -> sH2 (tiles 5,6) + x/u prefetch
        #pragma unroll
        for (int i=0;i<4;i++){ a[i][0]=0.f; a[i][1]=0.f; }
        float2 xpre; float upre = 0.f;
        {
            const int r = tid >> 7, q = tid & 127;
            const int tc = (t+2 <= TT-1) ? t+2 : TT-1;
            xpre = *(const float2*)&X[(((size_t)(n0+r)*TT) + tc)*DXX + q*2];
        }
        if (tid < 64){
            const int r = tid >> 5, j = tid & 31;
            upre = U[(((size_t)(n0+r)*TT) + t+1)*DUU + j];
        }
        stage32k((const char*)blob + (size_t)((tile+1)%40)*32768, sW[par^1], tid);
        tile_mac(sW[par], &sV[0][256], &sV[1][256], c, kq, a);
        tile++;
        ENDPH();
        stage32k((const char*)blob + (size_t)((tile+1)%40)*32768, sW[par^1], tid);
        tile_mac(sW[par], &sV[0][384], &sV[1][384], c, kq, a);
        tile++;
        reduce_out<1>(a, sRed, tid, 128, b_vp1, sH2[0], sH2[1], nullptr, nullptr);
        ENDPH();
        // ---- G4: logits = vp_w2 . h2 + b (tile 7) -> softmax -> sAl
        #pragma unroll
        for (int i=0;i<4;i++){ a[i][0]=0.f; a[i][1]=0.f; }
        stage32k((const char*)blob + (size_t)((tile+1)%40)*32768, sW[par^1], tid);
        tile_mac(sW[par], sH2[0], sH2[1], c, kq, a);
        tile++;
        reduce_out<0>(a, sRed, tid, 16, b_vp2, sL[0], sL[1], nullptr, nullptr);
        if (tid < 2){
            float mx = -1e30f;
            #pragma unroll
            for (int m = 0; m < 16; m++) mx = fmaxf(mx, sL[tid][m]);
            float ss = 0.f;
            #pragma unroll
            for (int m = 0; m < 16; m++){ float e = __expf(sL[tid][m]-mx); sAl[tid][m] = e; ss += e; }
            float inv = 1.f/ss;
            #pragma unroll
            for (int m = 0; m < 16; m++) sAl[tid][m] *= inv;
        }
        ENDPH();
        // ---- G5: z' = sum_m alpha_m * (ABC_m . [z|u|w]) (tiles 8..39)
        float z2[4][2];
        #pragma unroll
        for (int i=0;i<4;i++){ z2[i][0]=0.f; z2[i][1]=0.f; }
        for (int m = 0; m < 16; m++){
            #pragma unroll
            for (int i=0;i<4;i++){ a[i][0]=0.f; a[i][1]=0.f; }
            stage32k((const char*)blob + (size_t)((tile+1)%40)*32768, sW[par^1], tid);
            tile_mac(sW[par], &sV[0][256], &sV[1][256], c, kq, a);
            tile++;
            ENDPH();
            if (!(t == TT-2 && tile == 39))
                stage32k((const char*)blob + (size_t)((tile+1)%40)*32768, sW[par^1], tid);
            tile_mac(sW[par], &sV[0][384], &sV[1][384], c, kq, a);
            tile++;
            const float al0 = sAl[0][m], al1 = sAl[1][m];
            #pragma unroll
            for (int i=0;i<4;i++){ z2[i][0] += al0*a[i][0]; z2[i][1] += al1*a[i][1]; }
            if (m < 15) ENDPH();
        }
        // final reduce: z -> sV + global; then commit prefetched x/u
        reduce_out<0>(z2, sRed, tid, 128, 0.f, &sV[0][256], &sV[1][256],
                      &zb[(((size_t)(n0+0)*TT) + t+1)*DZZ],
                      &zb[(((size_t)(n0+1)*TT) + t+1)*DZZ]);
        {
            const int r = tid >> 7, q = tid & 127;
            sV[r][q*2]   = xpre.x;
            sV[r][q*2+1] = xpre.y;
        }
        if (tid < 64){
            const int r = tid >> 5, j = tid & 31;
            sV[r][384+j] = upre;
        }
        ENDPH();
    }
}

// ---------------------------------------------------------------------------
// K5: reconstruction + squared-error. 32 rows/block, bf16 tiles.
// ---------------------------------------------------------------------------
__global__ __launch_bounds__(256) void k_ob(const float* __restrict__ X,
        const float* __restrict__ zb,
        const float* __restrict__ b1, const float* __restrict__ b2,
        const unsigned short* __restrict__ blob, float* __restrict__ acc)
{
    __shared__ __align__(16) char  sW[2][32768];
    __shared__ __align__(16) float sZ[32*128];
    __shared__ __align__(16) float sH[32*128];
    __shared__ float redb[4];
    const int tid = threadIdx.x;
    const size_t row0 = (size_t)blockIdx.x * 32;
    const int g = tid & 127, rh = tid >> 7;
    for (int l = tid; l < 32*128; l += 256)
        sZ[l] = zb[(row0 + (size_t)(l >> 7))*DZZ + (l & 127)];
    stage32k((const char*)blob, sW[0], tid);
    asm volatile("s_waitcnt vmcnt(0)" ::: "memory");
    __syncthreads();
    // ph0: h = relu(ob_w1 . z + b1)
    stage32k((const char*)blob + 32768, sW[1], tid);
    float h[16];
    #pragma unroll
    for (int r = 0; r < 16; r++) h[r] = 0.f;
    #pragma unroll 4
    for (int s = 0; s < 16; s++){
        const uint32_t* wp = (const uint32_t*)(sW[0] + g*256 + ((s ^ (g & 7)) << 4));
        float wv[8];
        #pragma unroll
        for (int d = 0; d < 4; d++){
            uint32_t w2 = wp[d];
            wv[2*d]   = __uint_as_float(w2 << 16);
            wv[2*d+1] = __uint_as_float(w2 & 0xffff0000u);
        }
        #pragma unroll
        for (int r = 0; r < 16; r++){
            const float* ip = &sZ[(rh*16+r)*128 + s*8];
            float4 u0 = *(const float4*)ip;
            float4 u1 = *(const float4*)(ip+4);
            h[r] = fmaf(wv[0],u0.x, fmaf(wv[1],u0.y, fmaf(wv[2],u0.z, fmaf(wv[3],u0.w, h[r]))));
            h[r] = fmaf(wv[4],u1.x, fmaf(wv[5],u1.y, fmaf(wv[6],u1.z, fmaf(wv[7],u1.w, h[r]))));
        }
    }
    {
        const float bb1 = b1[g];
        #pragma unroll
        for (int r = 0; r < 16; r++){
            h[r] = fmaxf(h[r] + bb1, 0.f);
            sH[(rh*16+r)*128 + g] = h[r];
        }
    }
    asm volatile("s_waitcnt vmcnt(0)" ::: "memory");
    __syncthreads();
    // ph1/ph2: xrec cols [cb*128 + g], accumulate squared error
    float errs = 0.f;
    stage32k((const char*)blob + 65536, sW[0], tid);
    #pragma unroll 1
    for (int cb = 0; cb < 2; cb++){
        const char* wt = cb ? (const char*)sW[0] : (const char*)sW[1];
        float a2[16];
        #pragma unroll
        for (int r = 0; r < 16; r++) a2[r] = 0.f;
        #pragma unroll 4
        for (int s = 0; s < 16; s++){
            const uint32_t* wp = (const uint32_t*)(wt + g*256 + ((s ^ (g & 7)) << 4));
            float wv[8];
            #pragma unroll
            for (int d = 0; d < 4; d++){
                uint32_t w2 = wp[d];
                wv[2*d]   = __uint_as_float(w2 << 16);
                wv[2*d+1] = __uint_as_float(w2 & 0xffff0000u);
            }
            #pragma unroll
            for (int r = 0; r < 16; r++){
                const float* ip = &sH[(rh*16+r)*128 + s*8];
                float4 u0 = *(const float4*)ip;
                float4 u1 = *(const float4*)(ip+4);
                a2[r] = fmaf(wv[0],u0.x, fmaf(wv[1],u0.y, fmaf(wv[2],u0.z, fmaf(wv[3],u0.w, a2[r]))));
                a2[r] = fmaf(wv[4],u1.x, fmaf(wv[5],u1.y, fmaf(wv[6],u1.z, fmaf(wv[7],u1.w, a2[r]))));
            }
        }
        const float bb2 = b2[cb*128 + g];
        #pragma unroll
        for (int r = 0; r < 16; r++){
            float xr = a2[r] + bb2;
            float xv = X[(row0 + rh*16 + r)*DXX + cb*128 + g];
            float e = xv - xr;
            errs += e*e;
        }
        if (cb == 0){
            asm volatile("s_waitcnt vmcnt(0)" ::: "memory");
            __syncthreads();
        }
    }
    for (int o = 32; o > 0; o >>= 1) errs += __shfl_down(errs, o);
    if ((tid & 63) == 0) redb[tid >> 6] = errs;
    __syncthreads();
    if (tid == 0) atomicAdd(acc, redb[0]+redb[1]+redb[2]+redb[3]);
}

// ---------------------------------------------------------------------------
// K6: KL partial sums
// ---------------------------------------------------------------------------
__global__ __launch_bounds__(256) void k_kl(const float* __restrict__ wm,
                                            const float* __restrict__ wsd,
                                            float* __restrict__ acc)
{
    __shared__ float red[3][4];
    const int tid = threadIdx.x;
    const size_t base = (size_t)blockIdx.x * 4096 + tid;
    float s2 = 0.f, s3 = 0.f, s4 = 0.f;
    #pragma unroll
    for (int it = 0; it < 16; it++){
        size_t i = base + (size_t)it*256;
        float sd = wsd[i], mv = wm[i];
        s2 += sd; s3 += mv*mv; s4 += __logf(sd);
    }
    for (int o = 32; o > 0; o >>= 1){
        s2 += __shfl_down(s2, o); s3 += __shfl_down(s3, o); s4 += __shfl_down(s4, o);
    }
    if ((tid & 63) == 0){ int w = tid >> 6; red[0][w]=s2; red[1][w]=s3; red[2][w]=s4; }
    __syncthreads();
    if (tid == 0) atomicAdd(acc+1, red[0][0]+red[0][1]+red[0][2]+red[0][3]);
    if (tid == 1) atomicAdd(acc+2, red[1][0]+red[1][1]+red[1][2]+red[1][3]);
    if (tid == 2) atomicAdd(acc+3, red[2][0]+red[2][1]+red[2][2]+red[2][3]);
}

__global__ void k_final(const float* __restrict__ acc, float* __restrict__ out)
{
    if (threadIdx.x == 0 && blockIdx.x == 0){
        const double LOG2PI = 1.8378770664093453;
        double logpx_c = 0.5 * (double)NB * TT * DXX * LOG2PI;
        double kl = 0.5 * ((double)acc[1] + (double)acc[2]
                           - (double)NB*TT*DWW - (double)acc[3]);
        out[0] = (float)(0.5*(double)acc[0] + logpx_c + kl);
    }
}

// ---------------------------------------------------------------------------
extern "C" void kernel_launch(void* const* d_in, const int* in_sizes, int n_in,
                              void* d_out, int out_size, void* d_ws, size_t ws_size,
                              hipStream_t stream)
{
    (void)in_sizes; (void)n_in; (void)out_size; (void)ws_size;
    const float* x      = (const float*)d_in[0];
    const float* u      = (const float*)d_in[1];
    const float* eps1   = (const float*)d_in[2];
    const float* eps    = (const float*)d_in[3];
    const float* fw_Wih = (const float*)d_in[4];
    const float* fw_Whh = (const float*)d_in[5];
    const float* fw_b   = (const float*)d_in[6];
    const float* bw_Wih = (const float*)d_in[7];
    const float* bw_b   = (const float*)d_in[9];
    const float* i1w = (const float*)d_in[10];
    const float* i1b = (const float*)d_in[11];
    const float* i2w = (const float*)d_in[12];
    const float* i2b = (const float*)d_in[13];
    const float* z1w = (const float*)d_in[14];
    const float* z1b = (const float*)d_in[15];
    const float* z2w = (const float*)d_in[16];
    const float* z2b = (const float*)d_in[17];
    const float* wp_w1 = (const float*)d_in[18];
    const float* wp_b1 = (const float*)d_in[19];
    const float* wp_w2 = (const float*)d_in[20];
    const float* wp_b2 = (const float*)d_in[21];
    const float* vp_w1 = (const float*)d_in[22];
    const float* vp_b1 = (const float*)d_in[23];
    const float* vp_w2 = (const float*)d_in[24];
    const float* vp_b2 = (const float*)d_in[25];
    const float* ob_w1 = (const float*)d_in[26];
    const float* ob_b1 = (const float*)d_in[27];
    const float* ob_w2 = (const float*)d_in[28];
    const float* ob_b2 = (const float*)d_in[29];
    const float* Amat  = (const float*)d_in[30];
    const float* Bmat  = (const float*)d_in[31];
    const float* Cmat  = (const float*)d_in[32];
    float* out = (float*)d_out;

    // workspace layout (floats)
    float* ws  = (float*)d_ws;
    float* xg  = ws;                                     // 33,554,432
    float* h0  = xg  + (size_t)NB*TT*G4;                 //     65,536
    float* zb  = h0  + (size_t)NB*HHH;                   //  8,388,608
    float* wm  = zb  + (size_t)NB*TT*DZZ;                //  4,194,304
    float* wsd = wm  + (size_t)NB*TT*DWW;                //  4,194,304
    float* acc = wsd + (size_t)NB*TT*DWW;                //  64 (pad)
    unsigned short* bscan = (unsigned short*)(acc + 64);          // 40 tiles
    unsigned short* blstm = bscan + (size_t)40*16384;             // 4 tiles
    unsigned short* bob   = blstm + (size_t)4*16384;              // 3 tiles

    hipMemsetAsync(acc, 0, 4*sizeof(float), stream);

    k_prep<<<47, 256, 0, stream>>>(wp_w1, wp_w2, vp_w1, vp_w2, Amat, Bmat, Cmat,
                                   fw_Whh, ob_w1, ob_w2, bscan, blstm, bob);
    k_xg  <<<dim3(NB*TT/64, G4/64), 256, 0, stream>>>(x, fw_Wih, fw_b, xg);
    k_lstm<<<NB/2, 256, 0, stream>>>(xg, blstm, h0);
    k_init<<<NB/4, 256, 0, stream>>>(x, bw_Wih, bw_b, i1w, i1b, i2w, i2b,
                                     z1w, z1b, z2w, z2b, eps1, h0, zb, wm, wsd);
    k_scan<<<NB/2, 256, 0, stream>>>(x, u, eps, wp_b1, wp_b2, vp_b1, vp_b2,
                                     bscan, zb, wm, wsd);
    k_ob  <<<NB*TT/32, 256, 0, stream>>>(x, zb, ob_b1, ob_b2, bob, acc);
    k_kl  <<<NB*TT*DWW/4096, 256, 0, stream>>>(wm, wsd, acc);
    k_final<<<1, 64, 0, stream>>>(acc, out);
}